// Round 3
// baseline (682.308 us; speedup 1.0000x reference)
//
#include <hip/hip_runtime.h>
#include <math.h>

#define L_SPH 7
#define K_RAD 6
#define LK    42          // L*K
#define TPB   256
#define LDS_STRIDE 43     // 42 padded +1 -> conflict-free LDS transpose

// ---------------- host-side constants (replicates numpy bisection exactly) ---
// The reference casts Z and NORM to float32 (jnp.asarray(..., float32)); we do
// the bisection in f64 (bit-matching the reference host code) then round.

struct SBConsts {
    float z[L_SPH][K_RAD];     // Bessel zeros z_{l,n}, rounded to f32 like ref
    float nrm[L_SPH][K_RAD];   // normalizers c_{l,n}, rounded to f32 like ref
    float sphc[L_SPH];         // sqrt((2l+1)/4pi), f32
};

static double host_sph_jn(double r, int l) {
    double j = sin(r) / r;
    if (l == 0) return j;
    double jp = sin(r) / (r * r) - cos(r) / r;
    for (int i = 1; i < l; i++) {
        double t = (2.0 * i + 1.0) / r * jp - j;
        j = jp; jp = t;
    }
    return jp;
}

static SBConsts make_consts() {
    const int L = L_SPH, K = K_RAD;
    double prev[L + K];
    for (int i = 0; i < L + K; i++) prev[i] = (i + 1) * M_PI;
    int plen = L + K;
    double zeros[L_SPH][K_RAD];
    for (int n = 0; n < K; n++) zeros[0][n] = prev[n];
    for (int l = 1; l < L; l++) {
        int m = plen - 1;
        double lo[L + K], hi[L + K], flo[L + K];
        for (int i = 0; i < m; i++) {
            lo[i] = prev[i]; hi[i] = prev[i + 1];
            flo[i] = host_sph_jn(lo[i], l);
        }
        for (int it = 0; it < 100; it++) {
            for (int i = 0; i < m; i++) {
                double mid = 0.5 * (lo[i] + hi[i]);
                double fm  = host_sph_jn(mid, l);
                bool same  = (fm >= 0.0) == (flo[i] >= 0.0);
                if (same) { lo[i] = mid; flo[i] = fm; }
                else      { hi[i] = mid; }
            }
        }
        for (int i = 0; i < m; i++) prev[i] = 0.5 * (lo[i] + hi[i]);
        plen = m;
        for (int n = 0; n < K; n++) zeros[l][n] = prev[n];
    }
    SBConsts c;
    for (int l = 0; l < L; l++) {
        for (int n = 0; n < K; n++) {
            c.z[l][n] = (float)zeros[l][n];
            double j1 = host_sph_jn(zeros[l][n], l + 1);
            c.nrm[l][n] = (float)(1.0 / sqrt(0.5 * j1 * j1));
        }
        c.sphc[l] = (float)sqrt((2.0 * l + 1.0) / (4.0 * M_PI));
    }
    return c;
}

// ---------------- device helpers --------------------------------------------

// Correctly-rounded float32 sin/cos: evaluate in f64 (ocml, ~0.5 ulp f64) and
// round once to f32. Proxy for numpy's float32 trig (near-correctly-rounded at
// the small arguments that dominate the amplified entries).
__device__ __forceinline__ float sin_f32cr(float t) { return (float)sin((double)t); }
__device__ __forceinline__ float cos_f32cr(float t) { return (float)cos((double)t); }

// Bit-replicates the numpy float32 pipeline per edge:
//   dist = sqrt((dx*dx + dy*dy) + dz*dz)           (f32 each step)
//   x = dist/5 ; t = x*z32[l][n]
//   j0 = sin/t ; j1 = sin/t^2 - cos/t
//   j,jp = jp, ((2i+1)/t)*jp - j                   (div, mul, sub — NO fma)
//   rbf = (norm32*j) * env
// #pragma clang fp contract(off) prevents HIP's default fma contraction, which
// would change rounding and decorrelate the amplified (unstable) entries.
__device__ void edge_row_f32(float dx, float dy, float dz, const SBConsts& c,
                             float* row, float& nx, float& ny, float& nz) {
#pragma clang fp contract(off)
    float s = dx * dx;
    s = s + dy * dy;
    s = s + dz * dz;
    float dist = (float)sqrt((double)s);   // correctly-rounded f32 sqrt
    nx = dx / dist; ny = dy / dist; nz = dz / dist;
    float x = dist / 5.0f;                 // CUTOFF = 5
    // envelope p=6: 1/x - 28 x^5 + 48 x^6 - 21 x^7 (term order as reference;
    // not on the amplified path — last-ulp pow differences are harmless)
    float x2 = x * x, x4 = x2 * x2;
    float x5 = x4 * x, x6 = x5 * x, x7 = x6 * x;
    float env = 1.0f / x;
    env = env + (-28.0f) * x5;
    env = env + 48.0f * x6;
    env = env + (-21.0f) * x7;
#pragma unroll
    for (int l = 0; l < L_SPH; l++) {
#pragma unroll
        for (int n = 0; n < K_RAD; n++) {
            float t  = x * c.z[l][n];
            float sn = sin_f32cr(t);
            float co = cos_f32cr(t);
            float j  = sn / t;                 // j_0
            if (l > 0) {
                float t2 = t * t;
                float a1 = sn / t2;
                float a2 = co / t;
                float jp = a1 - a2;            // j_1 (cancellation preserved)
#pragma unroll
                for (int i = 1; i < l; i++) {
                    float q  = (float)(2 * i + 1) / t;
                    float m  = q * jp;
                    float nj = m - j;
                    j = jp; jp = nj;
                }
                j = jp;
            }
            float rb = c.nrm[l][n] * j;
            row[l * K_RAD + n] = rb * env;
        }
    }
}

__device__ __forceinline__ void legendre_cbf(float cs, const float* sphc,
                                             float* cbf) {
#pragma clang fp contract(off)
    float P0 = 1.0f, P1 = cs;
    cbf[0] = sphc[0];
    cbf[1] = sphc[1] * cs;
#pragma unroll
    for (int l = 1; l < L_SPH - 1; l++) {
        float a  = (float)(2 * l + 1) * cs;    // ((2l+1)*cos)*P_cur - l*P_prev
        float b  = a * P1;
        float d  = b - (float)l * P0;
        float Pn = d / (float)(l + 1);
        P0 = P1; P1 = Pn;
        cbf[l + 1] = sphc[l + 1] * Pn;
    }
}

// ---------------- kernel 1: per-edge rbf + normalized dirs -------------------

__global__ __launch_bounds__(TPB) void edge_kernel(
        const float* __restrict__ d, float* __restrict__ rbf,
        float4* __restrict__ nd4, int nE, SBConsts c) {
    int e = blockIdx.x * TPB + threadIdx.x;
    if (e >= nE) return;
    float dx = d[3 * e], dy = d[3 * e + 1], dz = d[3 * e + 2];
    float row[LK], nx, ny, nz;
    edge_row_f32(dx, dy, dz, c, row, nx, ny, nz);
    nd4[e] = make_float4(nx, ny, nz, 0.0f);
    float2* o = (float2*)(rbf + (size_t)e * LK);   // rows are 168B -> 8B aligned
#pragma unroll
    for (int k = 0; k < LK / 2; k++) o[k] = make_float2(row[2 * k], row[2 * k + 1]);
}

// ---------------- kernel 2: per-pair gather + Legendre + outer product -------

__global__ __launch_bounds__(TPB) void pair_kernel(
        const int* __restrict__ snd, const int* __restrict__ rcv,
        const float* __restrict__ rbf, const float4* __restrict__ nd4,
        float* __restrict__ out, int nP, SBConsts c) {
#pragma clang fp contract(off)
    __shared__ float so[TPB * LDS_STRIDE];         // 44032 B
    int p = blockIdx.x * TPB + threadIdx.x;
    if (p < nP) {
        int s = snd[p], r = rcv[p];
        float4 a = nd4[s], b = nd4[r];
        float cs = a.x * b.x;                      // left-to-right like einsum
        cs = cs + a.y * b.y;
        cs = cs + a.z * b.z;
        float cbf[L_SPH];
        legendre_cbf(cs, c.sphc, cbf);
        const float2* rowp = (const float2*)(rbf + (size_t)s * LK);
        float* my = &so[threadIdx.x * LDS_STRIDE];
#pragma unroll
        for (int k = 0; k < LK / 2; k++) {
            float2 v = rowp[k];
            my[2 * k]     = v.x * cbf[(2 * k) / K_RAD];
            my[2 * k + 1] = v.y * cbf[(2 * k + 1) / K_RAD];
        }
    }
    __syncthreads();
    // coalesced write of this block's contiguous TPB*42 output region
    size_t base  = (size_t)blockIdx.x * (TPB * LK);
    size_t limit = (size_t)nP * LK;
#pragma unroll
    for (int k = 0; k < LK; k++) {
        int idx = threadIdx.x + k * TPB;
        size_t g = base + idx;
        if (g < limit) {
            int pp = idx / LK, j = idx - pp * LK;
            out[g] = so[pp * LDS_STRIDE + j];
        }
    }
}

// ---------------- fallback: fully fused per-pair (no workspace) --------------

__global__ __launch_bounds__(TPB) void fused_kernel(
        const float* __restrict__ d, const int* __restrict__ snd,
        const int* __restrict__ rcv, float* __restrict__ out,
        int nP, SBConsts c) {
#pragma clang fp contract(off)
    int p = blockIdx.x * TPB + threadIdx.x;
    if (p >= nP) return;
    int s = snd[p], r = rcv[p];
    float row[LK], sx, sy, sz;
    edge_row_f32(d[3 * s], d[3 * s + 1], d[3 * s + 2], c, row, sx, sy, sz);
    float rx = d[3 * r], ry = d[3 * r + 1], rz = d[3 * r + 2];
    float t = rx * rx;  t = t + ry * ry;  t = t + rz * rz;
    float rd = (float)sqrt((double)t);
    float cs = sx * (rx / rd);
    cs = cs + sy * (ry / rd);
    cs = cs + sz * (rz / rd);
    float cbf[L_SPH];
    legendre_cbf(cs, c.sphc, cbf);
    float* o = out + (size_t)p * LK;
#pragma unroll
    for (int j = 0; j < LK; j++) o[j] = row[j] * cbf[j / K_RAD];
}

// ---------------- launch -----------------------------------------------------

extern "C" void kernel_launch(void* const* d_in, const int* in_sizes, int n_in,
                              void* d_out, int out_size, void* d_ws, size_t ws_size,
                              hipStream_t stream) {
    static SBConsts c = make_consts();   // host-side lazy init; same device work every call
    const float* dists = (const float*)d_in[0];
    const int*   snd   = (const int*)d_in[1];
    const int*   rcv   = (const int*)d_in[2];
    float*       out   = (float*)d_out;
    int nE = in_sizes[0] / 3;
    int nP = in_sizes[1];

    size_t rbf_bytes = ((size_t)nE * LK * sizeof(float) + 15) & ~(size_t)15;
    size_t need = rbf_bytes + (size_t)nE * sizeof(float4);

    if (ws_size >= need) {
        float*  rbf = (float*)d_ws;
        float4* nd4 = (float4*)((char*)d_ws + rbf_bytes);
        edge_kernel<<<(nE + TPB - 1) / TPB, TPB, 0, stream>>>(dists, rbf, nd4, nE, c);
        pair_kernel<<<(nP + TPB - 1) / TPB, TPB, 0, stream>>>(snd, rcv, rbf, nd4, out, nP, c);
    } else {
        fused_kernel<<<(nP + TPB - 1) / TPB, TPB, 0, stream>>>(dists, snd, rcv, out, nP, c);
    }
}